// Round 1
// 450.590 us; speedup vs baseline: 1.0054x; 1.0054x over previous
//
#include <hip/hip_runtime.h>

typedef _Float16 f16x8 __attribute__((ext_vector_type(8)));
typedef float    f32x4 __attribute__((ext_vector_type(4)));

#define MROWS 16384
#define NCOLS 256
#define KDIM  4096
#define BM    128
#define BK    32
#define LDA   40   // f16 stride per A row in LDS: 80 B = 5 odd granules -> conflict-free b128

// out layout (floats): idx[32768] | scores[32768] | pf[1048576] | imp[64] | load[64]
#define OUT_SCORES 32768
#define OUT_PF     65536
#define OUT_IMP    1114112
#define OUT_LOAD   1114176

// ---------------- Kernel 1: W fp32 -> frag-major f16 hi/lo planes ----------------
// frag-major: element (n,k) -> ((ksg*16 + NT)*64 + l)*8 + j
//   NT = n>>4, ksg = k>>5, l = (n&15) + 16*((k>>3)&3), j = k&7
__global__ __launch_bounds__(256) void wprep(const float* __restrict__ W,
                                             _Float16* __restrict__ wfHi,
                                             _Float16* __restrict__ wfLo) {
    int t  = blockIdx.x * 256 + threadIdx.x;   // 131072 threads: 256 n x 512 k8
    int n  = t >> 9;
    int k8 = t & 511;
    const float* src = W + ((size_t)n * KDIM + (size_t)k8 * 8);
    f16x8 hi, lo;
#pragma unroll
    for (int j = 0; j < 8; ++j) {
        float x = src[j];
        _Float16 h = (_Float16)x;
        hi[j] = h;
        lo[j] = (_Float16)(x - (float)h);
    }
    int NT  = n >> 4;
    int ksg = k8 >> 2;
    int l   = (n & 15) + ((k8 & 3) << 4);
    size_t dst = ((size_t)(ksg * 16 + NT) * 64 + (size_t)l) * 8;
    *(f16x8*)(wfHi + dst) = hi;
    *(f16x8*)(wfLo + dst) = lo;
}

// ---------------- Kernel 2: pipelined f16x2-split GEMM, K-split partials ----------------
// grid = 128*nsplit blocks, 256 threads (4 waves). Wave w owns cols [w*64, w*64+64).
// T14 depth-1 X prefetch + double-buffered LDS + ONE raw barrier per iter (no vmcnt drain).
__global__ __launch_bounds__(256, 2) void gemm3(const float* __restrict__ X,
        const _Float16* __restrict__ wfHi, const _Float16* __restrict__ wfLo,
        float* __restrict__ lsplit, int kQ) {
    __shared__ _Float16 aHi[2][BM * LDA];
    __shared__ _Float16 aLo[2][BM * LDA];

    const int tid  = threadIdx.x;
    const int lane = tid & 63;
    const int w    = tid >> 6;
    const int mt   = blockIdx.x & 127;
    const int s    = blockIdx.x >> 7;
    const int m0   = mt * BM;
    const int k0   = s * kQ;
    const int iters = kQ / BK;

    f32x4 acc[8][4];
#pragma unroll
    for (int a = 0; a < 8; ++a)
#pragma unroll
        for (int b = 0; b < 4; ++b) acc[a][b] = (f32x4){0.f, 0.f, 0.f, 0.f};

    // staging: thread -> (row = tid>>1, k-half = tid&1 covering 16 floats)
    const int sr = tid >> 1;
    const int sh = tid & 1;
    const float* xrow = X + ((size_t)(m0 + sr) * KDIM + (size_t)k0 + sh * 16);
    const int woff = sr * LDA + sh * 16;

    // A frag read base: row = mi*16 + (lane&15), k-granule = lane>>4
    const int roff = (lane & 15) * LDA + (lane >> 4) * 8;

    // B frag base: ((ksg*16 + NT)*64 + lane)*8, NT = w*4 + ni
    size_t bbase = (((size_t)(k0 >> 5) * 16 + (size_t)w * 4) * 64 + (size_t)lane) * 8;
    const _Float16* pBH = wfHi + bbase;
    const _Float16* pBL = wfLo + bbase;

    // prologue: X(0) into regs
    f32x4 xq[4];
#pragma unroll
    for (int q = 0; q < 4; ++q) xq[q] = *(const f32x4*)(xrow + q * 4);

    for (int i = 0; i < iters; ++i) {
        // B frags for this K-chunk (global; W planes are L2-resident)
        f16x8 bH[4], bL[4];
#pragma unroll
        for (int ni = 0; ni < 4; ++ni) {
            bH[ni] = *(const f16x8*)(pBH + (size_t)ni * 512);
            bL[ni] = *(const f16x8*)(pBL + (size_t)ni * 512);
        }
        pBH += 16 * 512;
        pBL += 16 * 512;

        // issue X(i+1) prefetch (stays in flight across the barrier; last iter
        // re-reads iter 0's span -- in-bounds, discarded)
        f32x4 xqN[4];
        {
            const float* xp = xrow + (size_t)((i + 1 < iters) ? (i + 1) : 0) * BK;
#pragma unroll
            for (int q = 0; q < 4; ++q) xqN[q] = *(const f32x4*)(xp + q * 4);
        }

        // split-convert X(i) (vmcnt wait for xq only; xqN stays outstanding)
        float xv[16];
#pragma unroll
        for (int q = 0; q < 4; ++q) {
            xv[q*4+0] = xq[q][0]; xv[q*4+1] = xq[q][1];
            xv[q*4+2] = xq[q][2]; xv[q*4+3] = xq[q][3];
        }
        f16x8 h0, h1, l0, l1;
#pragma unroll
        for (int j = 0; j < 8; ++j) {
            _Float16 ha = (_Float16)xv[j];
            h0[j] = ha; l0[j] = (_Float16)(xv[j] - (float)ha);
            _Float16 hb = (_Float16)xv[8 + j];
            h1[j] = hb; l1[j] = (_Float16)(xv[8 + j] - (float)hb);
        }

        // write this iter's LDS buffer (other waves are at most reading buf[i^1])
        _Float16* wAH = &aHi[i & 1][woff];
        _Float16* wAL = &aLo[i & 1][woff];
        *(f16x8*)(wAH)     = h0;
        *(f16x8*)(wAH + 8) = h1;
        *(f16x8*)(wAL)     = l0;
        *(f16x8*)(wAL + 8) = l1;

        // raw barrier: drain LDS ops only -- global prefetch stays in flight
        asm volatile("s_waitcnt lgkmcnt(0)" ::: "memory");
        __builtin_amdgcn_s_barrier();
        __builtin_amdgcn_sched_barrier(0);

        const _Float16* rAH = &aHi[i & 1][roff];
        const _Float16* rAL = &aLo[i & 1][roff];
        __builtin_amdgcn_s_setprio(1);
#pragma unroll
        for (int mi = 0; mi < 8; ++mi) {
            f16x8 aH = *(const f16x8*)(rAH + mi * 16 * LDA);
            f16x8 aL = *(const f16x8*)(rAL + mi * 16 * LDA);
#pragma unroll
            for (int ni = 0; ni < 4; ++ni) {
                acc[mi][ni] = __builtin_amdgcn_mfma_f32_16x16x32_f16(aH, bH[ni], acc[mi][ni], 0, 0, 0);
                acc[mi][ni] = __builtin_amdgcn_mfma_f32_16x16x32_f16(aH, bL[ni], acc[mi][ni], 0, 0, 0);
                acc[mi][ni] = __builtin_amdgcn_mfma_f32_16x16x32_f16(aL, bH[ni], acc[mi][ni], 0, 0, 0);
            }
        }
        __builtin_amdgcn_s_setprio(0);

        // rotate prefetch regs
#pragma unroll
        for (int q = 0; q < 4; ++q) xq[q] = xqN[q];
    }

    // epilogue: partial logits. C/D: col = lane&15, row = (lane>>4)*4 + reg (m89/m91)
    float* outp = lsplit + (size_t)s * ((size_t)MROWS * NCOLS);
#pragma unroll
    for (int mi = 0; mi < 8; ++mi) {
#pragma unroll
        for (int ni = 0; ni < 4; ++ni) {
            int col   = w * 64 + ni * 16 + (lane & 15);
            int rbase = m0 + mi * 16 + ((lane >> 4) << 2);
#pragma unroll
            for (int r = 0; r < 4; ++r)
                outp[(size_t)(rbase + r) * NCOLS + col] = acc[mi][ni][r];
        }
    }
}

// ---------------- Kernel 3: softmax / head-mean / top-2 / aux stats ----------------
// 16 lanes per row; lane i holds flat logits f = i + 16*t, t=0..15 (head g = t>>2,
// expert e = i + 16*(t&3) -> all 4 head values of an expert live in one lane).
__global__ __launch_bounds__(256) void finalize(const float* __restrict__ lsplit,
                                                int nsplit, float* __restrict__ out) {
    __shared__ float sImp[64], sLoad[64];
    const int tid = threadIdx.x;
    if (tid < 64) { sImp[tid] = 0.f; sLoad[tid] = 0.f; }
    __syncthreads();

    const int i   = tid & 15;
    const int grp = tid >> 4;
    const int r   = blockIdx.x * 16 + grp;

    float v[16];
#pragma unroll
    for (int t = 0; t < 16; ++t) {
        size_t off = (size_t)r * 256 + (size_t)i + 16 * t;
        float a = lsplit[off];
        for (int s = 1; s < nsplit; ++s)
            a += lsplit[(size_t)s * ((size_t)MROWS * NCOLS) + off];
        v[t] = a;
    }

    float hm[4];
#pragma unroll
    for (int g = 0; g < 4; ++g) {
        float m = fmaxf(fmaxf(v[4*g], v[4*g+1]), fmaxf(v[4*g+2], v[4*g+3]));
#pragma unroll
        for (int msk = 1; msk < 16; msk <<= 1)
            m = fmaxf(m, __shfl_xor(m, msk));
        hm[g] = m;
    }
    float p[16], inv[4];
#pragma unroll
    for (int g = 0; g < 4; ++g) {
        float sa = 0.f;
#pragma unroll
        for (int q = 0; q < 4; ++q) { p[4*g+q] = __expf(v[4*g+q] - hm[g]); sa += p[4*g+q]; }
#pragma unroll
        for (int msk = 1; msk < 16; msk <<= 1)
            sa += __shfl_xor(sa, msk);
        inv[g] = 1.f / sa;
    }

    float pf[4];
#pragma unroll
    for (int et = 0; et < 4; ++et) {
        pf[et] = 0.25f * (p[et] * inv[0] + p[4+et] * inv[1] + p[8+et] * inv[2] + p[12+et] * inv[3]);
        out[OUT_PF + (size_t)r * 64 + i + 16 * et] = pf[et];
        atomicAdd(&sImp[i + 16 * et], pf[et]);
        atomicAdd(&sLoad[i + 16 * et], pf[et] > 0.f ? 1.f : 0.f);
    }

    // top-2 with jax tie-break (equal value -> lower index)
    float v1 = -3.4e38f, v2 = -3.4e38f; int e1 = 0, e2 = 0;
#pragma unroll
    for (int et = 0; et < 4; ++et) {
        int e = i + 16 * et; float val = pf[et];
        if (val > v1) { v2 = v1; e2 = e1; v1 = val; e1 = e; }
        else if (val > v2) { v2 = val; e2 = e; }
    }
#pragma unroll
    for (int msk = 1; msk < 16; msk <<= 1) {
        float o1 = __shfl_xor(v1, msk); int oe1 = __shfl_xor(e1, msk);
        float o2 = __shfl_xor(v2, msk); int oe2 = __shfl_xor(e2, msk);
        bool ob = (o1 > v1) || (o1 == v1 && oe1 < e1);
        if (ob) {
            bool vb = (v1 > o2) || (v1 == o2 && e1 < oe2);
            v2 = vb ? v1 : o2; e2 = vb ? e1 : oe2;
            v1 = o1; e1 = oe1;
        } else {
            bool nb = (o1 > v2) || (o1 == v2 && oe1 < e2);
            v2 = nb ? o1 : v2; e2 = nb ? oe1 : e2;
        }
    }
    if (i == 0) {
        float den = fmaxf(v1 + v2, 1e-9f);
        out[(size_t)r * 2]              = (float)e1;
        out[(size_t)r * 2 + 1]          = (float)e2;
        out[OUT_SCORES + (size_t)r * 2]     = v1 / den;
        out[OUT_SCORES + (size_t)r * 2 + 1] = v2 / den;
    }
    __syncthreads();
    if (tid < 64) {
        atomicAdd(out + OUT_IMP  + tid, sImp[tid]  * (1.0f / 16384.0f));
        atomicAdd(out + OUT_LOAD + tid, sLoad[tid] * (1.0f / 16384.0f));
    }
}

extern "C" void kernel_launch(void* const* d_in, const int* in_sizes, int n_in,
                              void* d_out, int out_size, void* d_ws, size_t ws_size,
                              hipStream_t stream) {
    const float* X = (const float*)d_in[0];
    const float* W = (const float*)d_in[1];
    float* out = (float*)d_out;
    char* ws = (char*)d_ws;

    _Float16* wfHi = (_Float16*)ws;
    _Float16* wfLo = (_Float16*)(ws + (2u << 20));
    float* lsplit  = (float*)(ws + (4u << 20));

    const size_t per = 16u << 20;                       // one logits partial buffer
    int nsplit = (ws_size >= (4u << 20) + 4 * per) ? 4
               : (ws_size >= (4u << 20) + 2 * per) ? 2 : 1;

    // zero importance/load region of out (accumulated atomically by finalize)
    hipMemsetAsync((void*)(out + OUT_IMP), 0, 128 * sizeof(float), stream);

    wprep<<<512, 256, 0, stream>>>(W, wfHi, wfLo);
    gemm3<<<128 * nsplit, 256, 0, stream>>>(X, wfHi, wfLo, lsplit, KDIM / nsplit);
    finalize<<<1024, 256, 0, stream>>>(lsplit, nsplit, out);
}